// Round 22
// baseline (52.080 us; speedup 1.0000x reference)
//
#include <hip/hip_runtime.h>
#include <math.h>
#include <stdint.h>

#define NB  64
#define NT  512
#define ND  1024
#define NVT 6
#define NVY 20
#define TYPE_PAD_V 19
#define NE  2048
#define LOG2E 1.44269504088896340736f
#define LN2   0.69314718055994530942f

typedef float v2f __attribute__((ext_vector_type(2)));

// ws layout (floats):
//   featsT @ 0        : 512*384 = 196608   [t][b][6]
//   WtT    @ 196608   : 20*1024 = 20480    [v][d]
//   ws2    @ 217104   : 32*6*64*8 = 98304  chunk columns
//   gold   @ 315408   : 64
//   ce     @ 315472   : 2048
#define OFF_WTT 196608
#define OFF_WS2 217104
#define OFF_G   315408
#define OFF_CE  315472

// ---- K1: featsT = H @ W_tag + b_tag (LDS-staged W_tag) + WtT transpose ----
__global__ __launch_bounds__(256) void k1_tagfeats(const float* __restrict__ H,
                                                   const float* __restrict__ W_tag,
                                                   const float* __restrict__ b_tag,
                                                   const float* __restrict__ W_type,
                                                   float* __restrict__ ws) {
    float* featsT = ws;
    float* WtT    = ws + OFF_WTT;
    if (blockIdx.x < 32) {
        int tid = blockIdx.x * 256 + threadIdx.x;
        for (int i = tid; i < NVY * ND; i += 32 * 256)
            WtT[i] = W_type[(i & (ND - 1)) * NVY + (i >> 10)];
    }

    __shared__ float wlds[NVT][ND];
    for (int i = threadIdx.x; i < ND * NVT; i += 256) {
        int d = i / NVT, v = i % NVT;
        wlds[v][d] = W_tag[i];
    }
    __syncthreads();
    float bt[NVT];
#pragma unroll
    for (int v = 0; v < NVT; ++v) bt[v] = b_tag[v];

    const int lane = threadIdx.x & 63;
    const int wid  = threadIdx.x >> 6;
    const int qw   = lane >> 4;
    const int ql   = lane & 15;
    const int rowBase = blockIdx.x * 32;

#pragma unroll
    for (int it = 0; it < 2; ++it) {
        const int r = rowBase + it * 16 + wid * 4 + qw;
        const float4* hrow = (const float4*)(H + (size_t)r * ND);
        float acc[NVT] = {0.f, 0.f, 0.f, 0.f, 0.f, 0.f};
#pragma unroll
        for (int k = 0; k < 16; ++k) {
            float4 h = hrow[ql + 16 * k];
#pragma unroll
            for (int v = 0; v < NVT; ++v) {
                float4 w = ((const float4*)&wlds[v][0])[ql + 16 * k];
                acc[v] += h.x * w.x + h.y * w.y + h.z * w.z + h.w * w.w;
            }
        }
#pragma unroll
        for (int v = 0; v < NVT; ++v) {
#pragma unroll
            for (int off = 8; off >= 1; off >>= 1)
                acc[v] += __shfl_xor(acc[v], off);
        }
        const int bb = r >> 9;
        const int tt = r & (NT - 1);
#pragma unroll
        for (int v = 0; v < NVT; ++v)
            if (ql == v) featsT[(size_t)tt * 384 + bb * 6 + v] = acc[v] + bt[v];
    }
}

// ---- K2: entity-PAIRS(0..1023) first, then chunks(1024..1215), gold(1216..1279) ----
__global__ __launch_bounds__(64) void k2_fused(
    const float* __restrict__ H,
    const float* __restrict__ b_type,
    const float* __restrict__ crf_start,
    const float* __restrict__ crf_end,
    const float* __restrict__ crf_trans,
    const int* __restrict__ tag_ids,
    const int* __restrict__ seq_lens,
    const int* __restrict__ ent_sid,
    const int* __restrict__ ent_st,
    const int* __restrict__ ent_en,
    const int* __restrict__ ent_ty,
    float* __restrict__ ws) {
    const float* featsT = ws;
    const float* WtT    = ws + OFF_WTT;
    float* ws2          = ws + OFF_WS2;
    float* goldv        = ws + OFF_G;
    float* cev          = ws + OFF_CE;
    __shared__ int stag[NT];
    __shared__ float trLp[NVT * NVT];
    const int lane = threadIdx.x;

    if (blockIdx.x < NE / 2) {
        // ---------- entity pair: one wave, two entities share the WtT stream ----
        const int ea = blockIdx.x * 2;
        const int eb = ea + 1;
        const int ba = ent_sid[ea], sa = ent_st[ea], na = ent_en[ea], tya = ent_ty[ea];
        const int bb = ent_sid[eb], sb = ent_st[eb], nb = ent_en[eb], tyb = ent_ty[eb];
        float4 sva[4], svb[4];
#pragma unroll
        for (int k = 0; k < 4; ++k) {
            sva[k].x = 0.f; sva[k].y = 0.f; sva[k].z = 0.f; sva[k].w = 0.f;
            svb[k].x = 0.f; svb[k].y = 0.f; svb[k].z = 0.f; svb[k].w = 0.f;
        }
        for (int t = sa; t < na; ++t) {
            const float4* hr = (const float4*)(H + ((size_t)ba * NT + t) * ND);
#pragma unroll
            for (int k = 0; k < 4; ++k) {
                float4 h = hr[lane + 64 * k];
                sva[k].x += h.x; sva[k].y += h.y; sva[k].z += h.z; sva[k].w += h.w;
            }
        }
        for (int t = sb; t < nb; ++t) {
            const float4* hr = (const float4*)(H + ((size_t)bb * NT + t) * ND);
#pragma unroll
            for (int k = 0; k < 4; ++k) {
                float4 h = hr[lane + 64 * k];
                svb[k].x += h.x; svb[k].y += h.y; svb[k].z += h.z; svb[k].w += h.w;
            }
        }
        const float inva = 1.0f / (float)(na - sa);
        const float invb = 1.0f / (float)(nb - sb);
        float fa[NVY], fb[NVY];
#pragma unroll
        for (int v = 0; v < NVY; ++v) {
            const float4* wv = (const float4*)(WtT + v * ND);
            float pa = 0.0f, pb = 0.0f;
#pragma unroll
            for (int k = 0; k < 4; ++k) {
                float4 w = wv[lane + 64 * k];
                pa += sva[k].x * w.x + sva[k].y * w.y + sva[k].z * w.z + sva[k].w * w.w;
                pb += svb[k].x * w.x + svb[k].y * w.y + svb[k].z * w.z + svb[k].w * w.w;
            }
#pragma unroll
            for (int off = 32; off >= 1; off >>= 1) {
                pa += __shfl_xor(pa, off);
                pb += __shfl_xor(pb, off);
            }
            fa[v] = pa * inva + b_type[v];
            fb[v] = pb * invb + b_type[v];
        }
        float mxa = -3.0e38f, mxb = -3.0e38f;
#pragma unroll
        for (int v = 0; v < NVY; ++v) {
            mxa = fmaxf(mxa, fa[v]);
            mxb = fmaxf(mxb, fb[v]);
        }
        float suma = 0.0f, sumb = 0.0f, golda = 0.0f, goldb = 0.0f;
#pragma unroll
        for (int v = 0; v < NVY; ++v) {
            suma += __expf(fa[v] - mxa);
            sumb += __expf(fb[v] - mxb);
            if (v == tya) golda = fa[v];
            if (v == tyb) goldb = fb[v];
        }
        float lsea = mxa + __logf(suma);
        float lseb = mxb + __logf(sumb);
        if (lane == 0) {
            cev[ea] = (tya != TYPE_PAD_V) ? (lsea - golda) : 0.0f;
            cev[eb] = (tyb != TYPE_PAD_V) ? (lseb - goldb) : 0.0f;
        }
    } else if (blockIdx.x < NE / 2 + 192) {
        // ---------- chunk block: column k of P_c, lane = sample b ----------
        const int cb = blockIdx.x - NE / 2;
        const int c = cb / 6;
        const int k = cb - 6 * c;
        const int b = lane;
        const int L = seq_lens[b];
        float F[NVT][NVT];
#pragma unroll
        for (int i = 0; i < NVT; ++i)
#pragma unroll
            for (int j = 0; j < NVT; ++j)
                F[i][j] = __builtin_amdgcn_exp2f(crf_trans[i * NVT + j] * LOG2E);
        const char* pf = (const char*)featsT + b * 24;
        v2f Ebuf[16][3];
#pragma unroll
        for (int u = 0; u < 16; ++u) {
            const v2f* p = (const v2f*)(pf + (size_t)(16 * c + 1 + u) * 1536);
            Ebuf[u][0] = p[0]; Ebuf[u][1] = p[1]; Ebuf[u][2] = p[2];
        }
        float v0, v1, v2, v3, v4, v5;
        v0 = (k == 0) ? 1.f : 0.f; v1 = (k == 1) ? 1.f : 0.f; v2 = (k == 2) ? 1.f : 0.f;
        v3 = (k == 3) ? 1.f : 0.f; v4 = (k == 4) ? 1.f : 0.f; v5 = (k == 5) ? 1.f : 0.f;
        int isc = 0;
#pragma unroll
        for (int u = 0; u < 16; ++u) {
            float e0 = __builtin_amdgcn_exp2f(Ebuf[u][0].x * LOG2E);
            float e1 = __builtin_amdgcn_exp2f(Ebuf[u][0].y * LOG2E);
            float e2 = __builtin_amdgcn_exp2f(Ebuf[u][1].x * LOG2E);
            float e3 = __builtin_amdgcn_exp2f(Ebuf[u][1].y * LOG2E);
            float e4 = __builtin_amdgcn_exp2f(Ebuf[u][2].x * LOG2E);
            float e5 = __builtin_amdgcn_exp2f(Ebuf[u][2].y * LOG2E);
            bool ok = (16 * c + 1 + u) < L;
            float g[NVT];
#pragma unroll
            for (int j = 0; j < NVT; ++j) {
                float s = F[0][j] * v0;
                s = __builtin_fmaf(F[1][j], v1, s);
                s = __builtin_fmaf(F[2][j], v2, s);
                s = __builtin_fmaf(F[3][j], v3, s);
                s = __builtin_fmaf(F[4][j], v4, s);
                s = __builtin_fmaf(F[5][j], v5, s);
                g[j] = s;
            }
            v0 = ok ? e0 * g[0] : v0;  v1 = ok ? e1 * g[1] : v1;
            v2 = ok ? e2 * g[2] : v2;  v3 = ok ? e3 * g[3] : v3;
            v4 = ok ? e4 * g[4] : v4;  v5 = ok ? e5 * g[5] : v5;
            if ((u & 3) == 3) {   // exact power-of-2 rescale
                float qmax = fmaxf(fmaxf(fmaxf(v0, v1), v2), fmaxf(fmaxf(v3, v4), v5));
                uint32_t eb2 = __float_as_uint(qmax) >> 23;
                float ri = __uint_as_float((uint32_t)(253 - eb2) << 23);
                v0 *= ri; v1 *= ri; v2 *= ri; v3 *= ri; v4 *= ri; v5 *= ri;
                isc += (int)eb2 - 126;
            }
        }
        float4* dst = (float4*)(ws2 + (((size_t)c * 6 + k) * 64 + b) * 8);
        dst[0] = make_float4(v0, v1, v2, v3);
        dst[1] = make_float4(v4, v5, (float)isc, 0.0f);
    } else {
        // ---------- gold path score: plain store ----------
        const int b = blockIdx.x - NE / 2 - 192;
        for (int i = lane; i < NT; i += 64) stag[i] = tag_ids[b * NT + i];
        if (lane < NVT * NVT) trLp[lane] = crf_trans[lane];
        __syncthreads();
        const int L = seq_lens[b];
        float g = 0.0f;
#pragma unroll
        for (int k = 0; k < NT / 64; ++k) {
            int t = lane + 64 * k;
            if (t < L) {
                int tg = stag[t];
                g += featsT[(size_t)t * 384 + b * 6 + tg];
                if (t >= 1) g += trLp[stag[t - 1] * NVT + tg];
            }
        }
#pragma unroll
        for (int off = 32; off >= 1; off >>= 1) g += __shfl_xor(g, off);
        if (lane == 0)
            goldv[b] = g + crf_start[stag[0]] + crf_end[stag[L - 1]];
    }
}

// ---- K3: 64 blocks (one per sample). Entity segsum + 32-step combine from LDS. ----
__global__ __launch_bounds__(256) void k3_final(
    const float* __restrict__ crf_start,
    const float* __restrict__ crf_end,
    const int* __restrict__ ent_sid,
    const float* __restrict__ ws,
    float* __restrict__ out) {
    const float* featsT = ws;
    const float* ws2    = ws + OFF_WS2;
    const float* goldv  = ws + OFF_G;
    const float* cev    = ws + OFF_CE;
    __shared__ float mats[192 * 8];
    __shared__ float part[256];
    const int b   = blockIdx.x;
    const int tid = threadIdx.x;

    {
        const int4*   s4 = (const int4*)ent_sid;
        const float4* c4 = (const float4*)cev;
        float acc = 0.0f;
#pragma unroll
        for (int i = 0; i < 2; ++i) {
            int4   s = s4[tid * 2 + i];
            float4 c = c4[tid * 2 + i];
            acc += (s.x == b) ? c.x : 0.0f;
            acc += (s.y == b) ? c.y : 0.0f;
            acc += (s.z == b) ? c.z : 0.0f;
            acc += (s.w == b) ? c.w : 0.0f;
        }
        part[tid] = acc;
    }
    if (tid < 192) {
        const float4* src = (const float4*)(ws2 + ((size_t)tid * 64 + b) * 8);
        float4 a = src[0], d = src[1];
        ((float4*)&mats[tid * 8])[0] = a;
        ((float4*)&mats[tid * 8])[1] = d;
    }
    __syncthreads();
    if (tid < 128) part[tid] += part[tid + 128];
    __syncthreads();
    if (tid < 64) {
        float v = part[tid] + part[tid + 64];
#pragma unroll
        for (int off = 32; off >= 1; off >>= 1) v += __shfl_xor(v, off);
        if (tid == 0) part[0] = v;
    }
    __syncthreads();

    if (tid < 64) {
        float a0[NVT];
#pragma unroll
        for (int j = 0; j < NVT; ++j) a0[j] = crf_start[j] + featsT[b * 6 + j];
        float m0 = fmaxf(fmaxf(fmaxf(a0[0], a0[1]), a0[2]),
                         fmaxf(fmaxf(a0[3], a0[4]), a0[5]));
        float q[6];
#pragma unroll
        for (int j = 0; j < NVT; ++j)
            q[j] = __builtin_amdgcn_exp2f((a0[j] - m0) * LOG2E);
        float mAcc = m0 * LOG2E;

#pragma unroll 1
        for (int c = 0; c < 32; ++c) {
            const float* m = &mats[c * 48];
            float4 c0a = ((const float4*)m)[0],  c0b = ((const float4*)m)[1];
            float4 c1a = ((const float4*)m)[2],  c1b = ((const float4*)m)[3];
            float4 c2a = ((const float4*)m)[4],  c2b = ((const float4*)m)[5];
            float4 c3a = ((const float4*)m)[6],  c3b = ((const float4*)m)[7];
            float4 c4a = ((const float4*)m)[8],  c4b = ((const float4*)m)[9];
            float4 c5a = ((const float4*)m)[10], c5b = ((const float4*)m)[11];
            float s0 = c0b.z, s1 = c1b.z, s2 = c2b.z, s3 = c3b.z, s4 = c4b.z, s5 = c5b.z;
            float im = fmaxf(fmaxf(fmaxf(s0, s1), fmaxf(s2, s3)), fmaxf(s4, s5));
            float w0 = q[0] * __builtin_amdgcn_exp2f(s0 - im);
            float w1 = q[1] * __builtin_amdgcn_exp2f(s1 - im);
            float w2 = q[2] * __builtin_amdgcn_exp2f(s2 - im);
            float w3 = q[3] * __builtin_amdgcn_exp2f(s3 - im);
            float w4 = q[4] * __builtin_amdgcn_exp2f(s4 - im);
            float w5 = q[5] * __builtin_amdgcn_exp2f(s5 - im);
            float n0 = c0a.x * w0, n1 = c0a.y * w0, n2 = c0a.z * w0,
                  n3 = c0a.w * w0, n4 = c0b.x * w0, n5 = c0b.y * w0;
            n0 = __builtin_fmaf(c1a.x, w1, n0); n1 = __builtin_fmaf(c1a.y, w1, n1);
            n2 = __builtin_fmaf(c1a.z, w1, n2); n3 = __builtin_fmaf(c1a.w, w1, n3);
            n4 = __builtin_fmaf(c1b.x, w1, n4); n5 = __builtin_fmaf(c1b.y, w1, n5);
            n0 = __builtin_fmaf(c2a.x, w2, n0); n1 = __builtin_fmaf(c2a.y, w2, n1);
            n2 = __builtin_fmaf(c2a.z, w2, n2); n3 = __builtin_fmaf(c2a.w, w2, n3);
            n4 = __builtin_fmaf(c2b.x, w2, n4); n5 = __builtin_fmaf(c2b.y, w2, n5);
            n0 = __builtin_fmaf(c3a.x, w3, n0); n1 = __builtin_fmaf(c3a.y, w3, n1);
            n2 = __builtin_fmaf(c3a.z, w3, n2); n3 = __builtin_fmaf(c3a.w, w3, n3);
            n4 = __builtin_fmaf(c3b.x, w3, n4); n5 = __builtin_fmaf(c3b.y, w3, n5);
            n0 = __builtin_fmaf(c4a.x, w4, n0); n1 = __builtin_fmaf(c4a.y, w4, n1);
            n2 = __builtin_fmaf(c4a.z, w4, n2); n3 = __builtin_fmaf(c4a.w, w4, n3);
            n4 = __builtin_fmaf(c4b.x, w4, n4); n5 = __builtin_fmaf(c4b.y, w4, n5);
            n0 = __builtin_fmaf(c5a.x, w5, n0); n1 = __builtin_fmaf(c5a.y, w5, n1);
            n2 = __builtin_fmaf(c5a.z, w5, n2); n3 = __builtin_fmaf(c5a.w, w5, n3);
            n4 = __builtin_fmaf(c5b.x, w5, n4); n5 = __builtin_fmaf(c5b.y, w5, n5);
            float qm = fmaxf(fmaxf(fmaxf(n0, n1), n2), fmaxf(fmaxf(n3, n4), n5));
            uint32_t eb2 = __float_as_uint(qm) >> 23;
            float ri = __uint_as_float((uint32_t)(253 - eb2) << 23);
            q[0] = n0 * ri; q[1] = n1 * ri; q[2] = n2 * ri;
            q[3] = n3 * ri; q[4] = n4 * ri; q[5] = n5 * ri;
            mAcc += im + (float)((int)eb2 - 126);
        }

        float zs = 0.0f;
#pragma unroll
        for (int j = 0; j < NVT; ++j)
            zs += q[j] * __builtin_amdgcn_exp2f(crf_end[j] * LOG2E);
        float logZ = LN2 * (mAcc + __builtin_amdgcn_logf(zs));
        if (tid == 0)
            out[b] = logZ - goldv[b] + part[0];
    }
}

extern "C" void kernel_launch(void* const* d_in, const int* in_sizes, int n_in,
                              void* d_out, int out_size, void* d_ws, size_t ws_size,
                              hipStream_t stream) {
    const float* H         = (const float*)d_in[0];
    const float* W_tag     = (const float*)d_in[1];
    const float* b_tag     = (const float*)d_in[2];
    const float* W_type    = (const float*)d_in[3];
    const float* b_type    = (const float*)d_in[4];
    const float* crf_start = (const float*)d_in[5];
    const float* crf_end   = (const float*)d_in[6];
    const float* crf_trans = (const float*)d_in[7];
    const int* tag_ids     = (const int*)d_in[8];
    const int* seq_lens    = (const int*)d_in[9];
    const int* ent_sid     = (const int*)d_in[10];
    const int* ent_st      = (const int*)d_in[11];
    const int* ent_en      = (const int*)d_in[12];
    const int* ent_ty      = (const int*)d_in[13];
    float* out = (float*)d_out;
    float* ws  = (float*)d_ws;

    hipLaunchKernelGGL(k1_tagfeats, dim3(1024), dim3(256), 0, stream,
                       H, W_tag, b_tag, W_type, ws);
    hipLaunchKernelGGL(k2_fused, dim3(NE / 2 + 192 + NB), dim3(64), 0, stream,
                       H, b_type, crf_start, crf_end, crf_trans,
                       tag_ids, seq_lens, ent_sid, ent_st, ent_en, ent_ty, ws);
    hipLaunchKernelGGL(k3_final, dim3(NB), dim3(256), 0, stream,
                       crf_start, crf_end, ent_sid, ws, out);
}

// Round 23
// 51.155 us; speedup vs baseline: 1.0181x; 1.0181x over previous
//
#include <hip/hip_runtime.h>
#include <math.h>
#include <stdint.h>

#define NB  64
#define NT  512
#define ND  1024
#define NVT 6
#define NVY 20
#define TYPE_PAD_V 19
#define NE  2048
#define LOG2E 1.44269504088896340736f
#define LN2   0.69314718055994530942f

typedef float v2f __attribute__((ext_vector_type(2)));

// ws layout (floats):
//   featsT @ 0        : 512*384 = 196608   [t][b][6]
//   WtT    @ 196608   : 20*1024 = 20480    [v][d]
//   ws2    @ 217104   : 32*6*64*8 = 98304  chunk columns
//   gold   @ 315408   : 64
//   ce     @ 315472   : 2048
#define OFF_WTT 196608
#define OFF_WS2 217104
#define OFF_G   315408
#define OFF_CE  315472

// ---- K1: featsT = H @ W_tag + b_tag (LDS-staged W_tag) + WtT transpose ----
__global__ __launch_bounds__(256) void k1_tagfeats(const float* __restrict__ H,
                                                   const float* __restrict__ W_tag,
                                                   const float* __restrict__ b_tag,
                                                   const float* __restrict__ W_type,
                                                   float* __restrict__ ws) {
    float* featsT = ws;
    float* WtT    = ws + OFF_WTT;
    if (blockIdx.x < 32) {
        int tid = blockIdx.x * 256 + threadIdx.x;
        for (int i = tid; i < NVY * ND; i += 32 * 256)
            WtT[i] = W_type[(i & (ND - 1)) * NVY + (i >> 10)];
    }

    __shared__ float wlds[NVT][ND];
    for (int i = threadIdx.x; i < ND * NVT; i += 256) {
        int d = i / NVT, v = i % NVT;
        wlds[v][d] = W_tag[i];
    }
    __syncthreads();
    float bt[NVT];
#pragma unroll
    for (int v = 0; v < NVT; ++v) bt[v] = b_tag[v];

    const int lane = threadIdx.x & 63;
    const int wid  = threadIdx.x >> 6;
    const int qw   = lane >> 4;
    const int ql   = lane & 15;
    const int rowBase = blockIdx.x * 32;

#pragma unroll
    for (int it = 0; it < 2; ++it) {
        const int r = rowBase + it * 16 + wid * 4 + qw;
        const float4* hrow = (const float4*)(H + (size_t)r * ND);
        float acc[NVT] = {0.f, 0.f, 0.f, 0.f, 0.f, 0.f};
#pragma unroll
        for (int k = 0; k < 16; ++k) {
            float4 h = hrow[ql + 16 * k];
#pragma unroll
            for (int v = 0; v < NVT; ++v) {
                float4 w = ((const float4*)&wlds[v][0])[ql + 16 * k];
                acc[v] += h.x * w.x + h.y * w.y + h.z * w.z + h.w * w.w;
            }
        }
#pragma unroll
        for (int v = 0; v < NVT; ++v) {
#pragma unroll
            for (int off = 8; off >= 1; off >>= 1)
                acc[v] += __shfl_xor(acc[v], off);
        }
        const int bb = r >> 9;
        const int tt = r & (NT - 1);
#pragma unroll
        for (int v = 0; v < NVT; ++v)
            if (ql == v) featsT[(size_t)tt * 384 + bb * 6 + v] = acc[v] + bt[v];
    }
}

// ---- K2: entities(0..2047) FIRST, then chunks(2048..2239), gold(2240..2303) ----
__global__ __launch_bounds__(64) void k2_fused(
    const float* __restrict__ H,
    const float* __restrict__ b_type,
    const float* __restrict__ crf_start,
    const float* __restrict__ crf_end,
    const float* __restrict__ crf_trans,
    const int* __restrict__ tag_ids,
    const int* __restrict__ seq_lens,
    const int* __restrict__ ent_sid,
    const int* __restrict__ ent_st,
    const int* __restrict__ ent_en,
    const int* __restrict__ ent_ty,
    float* __restrict__ ws) {
    const float* featsT = ws;
    const float* WtT    = ws + OFF_WTT;
    float* ws2          = ws + OFF_WS2;
    float* goldv        = ws + OFF_G;
    float* cev          = ws + OFF_CE;
    __shared__ int stag[NT];
    __shared__ float trLp[NVT * NVT];
    const int lane = threadIdx.x;

    if (blockIdx.x < NE) {
        // ---------- entity path: one wave per entity, plain store ----------
        const int e  = blockIdx.x;
        const int bb = ent_sid[e];
        const int s  = ent_st[e];
        const int en = ent_en[e];
        const int ty = ent_ty[e];
        float4 sv[4];
#pragma unroll
        for (int k = 0; k < 4; ++k) { sv[k].x = 0.f; sv[k].y = 0.f; sv[k].z = 0.f; sv[k].w = 0.f; }
        for (int t = s; t < en; ++t) {
            const float4* hr = (const float4*)(H + ((size_t)bb * NT + t) * ND);
#pragma unroll
            for (int k = 0; k < 4; ++k) {
                float4 h = hr[lane + 64 * k];
                sv[k].x += h.x; sv[k].y += h.y; sv[k].z += h.z; sv[k].w += h.w;
            }
        }
        const float inv = 1.0f / (float)(en - s);
        float f[NVY];
#pragma unroll
        for (int v = 0; v < NVY; ++v) {
            const float4* wv = (const float4*)(WtT + v * ND);
            float p = 0.0f;
#pragma unroll
            for (int k = 0; k < 4; ++k) {
                float4 w = wv[lane + 64 * k];
                p += sv[k].x * w.x + sv[k].y * w.y + sv[k].z * w.z + sv[k].w * w.w;
            }
#pragma unroll
            for (int off = 32; off >= 1; off >>= 1) p += __shfl_xor(p, off);
            f[v] = p * inv + b_type[v];
        }
        float mx = -3.0e38f;
#pragma unroll
        for (int v = 0; v < NVY; ++v) mx = fmaxf(mx, f[v]);
        float sum = 0.0f, goldf = 0.0f;
#pragma unroll
        for (int v = 0; v < NVY; ++v) {
            sum += __expf(f[v] - mx);
            if (v == ty) goldf = f[v];
        }
        float lse = mx + __logf(sum);
        if (lane == 0) cev[e] = (ty != TYPE_PAD_V) ? (lse - goldf) : 0.0f;
    } else if (blockIdx.x < NE + 192) {
        // ---------- chunk block: column k of P_c, lane = sample b ----------
        const int cb = blockIdx.x - NE;
        const int c = cb / 6;
        const int k = cb - 6 * c;
        const int b = lane;
        const int L = seq_lens[b];
        float F[NVT][NVT];
#pragma unroll
        for (int i = 0; i < NVT; ++i)
#pragma unroll
            for (int j = 0; j < NVT; ++j)
                F[i][j] = __builtin_amdgcn_exp2f(crf_trans[i * NVT + j] * LOG2E);
        const char* pf = (const char*)featsT + b * 24;
        v2f Ebuf[16][3];
#pragma unroll
        for (int u = 0; u < 16; ++u) {
            const v2f* p = (const v2f*)(pf + (size_t)(16 * c + 1 + u) * 1536);
            Ebuf[u][0] = p[0]; Ebuf[u][1] = p[1]; Ebuf[u][2] = p[2];
        }
        float v0, v1, v2, v3, v4, v5;
        v0 = (k == 0) ? 1.f : 0.f; v1 = (k == 1) ? 1.f : 0.f; v2 = (k == 2) ? 1.f : 0.f;
        v3 = (k == 3) ? 1.f : 0.f; v4 = (k == 4) ? 1.f : 0.f; v5 = (k == 5) ? 1.f : 0.f;
        int isc = 0;
#pragma unroll
        for (int u = 0; u < 16; ++u) {
            float e0 = __builtin_amdgcn_exp2f(Ebuf[u][0].x * LOG2E);
            float e1 = __builtin_amdgcn_exp2f(Ebuf[u][0].y * LOG2E);
            float e2 = __builtin_amdgcn_exp2f(Ebuf[u][1].x * LOG2E);
            float e3 = __builtin_amdgcn_exp2f(Ebuf[u][1].y * LOG2E);
            float e4 = __builtin_amdgcn_exp2f(Ebuf[u][2].x * LOG2E);
            float e5 = __builtin_amdgcn_exp2f(Ebuf[u][2].y * LOG2E);
            bool ok = (16 * c + 1 + u) < L;
            float g[NVT];
#pragma unroll
            for (int j = 0; j < NVT; ++j) {
                float s = F[0][j] * v0;
                s = __builtin_fmaf(F[1][j], v1, s);
                s = __builtin_fmaf(F[2][j], v2, s);
                s = __builtin_fmaf(F[3][j], v3, s);
                s = __builtin_fmaf(F[4][j], v4, s);
                s = __builtin_fmaf(F[5][j], v5, s);
                g[j] = s;
            }
            v0 = ok ? e0 * g[0] : v0;  v1 = ok ? e1 * g[1] : v1;
            v2 = ok ? e2 * g[2] : v2;  v3 = ok ? e3 * g[3] : v3;
            v4 = ok ? e4 * g[4] : v4;  v5 = ok ? e5 * g[5] : v5;
            if ((u & 3) == 3) {   // exact power-of-2 rescale
                float qmax = fmaxf(fmaxf(fmaxf(v0, v1), v2), fmaxf(fmaxf(v3, v4), v5));
                uint32_t eb = __float_as_uint(qmax) >> 23;
                float ri = __uint_as_float((uint32_t)(253 - eb) << 23);
                v0 *= ri; v1 *= ri; v2 *= ri; v3 *= ri; v4 *= ri; v5 *= ri;
                isc += (int)eb - 126;
            }
        }
        float4* dst = (float4*)(ws2 + (((size_t)c * 6 + k) * 64 + b) * 8);
        dst[0] = make_float4(v0, v1, v2, v3);
        dst[1] = make_float4(v4, v5, (float)isc, 0.0f);
    } else {
        // ---------- gold path score: plain store ----------
        const int b = blockIdx.x - NE - 192;
        for (int i = lane; i < NT; i += 64) stag[i] = tag_ids[b * NT + i];
        if (lane < NVT * NVT) trLp[lane] = crf_trans[lane];
        __syncthreads();
        const int L = seq_lens[b];
        float g = 0.0f;
#pragma unroll
        for (int k = 0; k < NT / 64; ++k) {
            int t = lane + 64 * k;
            if (t < L) {
                int tg = stag[t];
                g += featsT[(size_t)t * 384 + b * 6 + tg];
                if (t >= 1) g += trLp[stag[t - 1] * NVT + tg];
            }
        }
#pragma unroll
        for (int off = 32; off >= 1; off >>= 1) g += __shfl_xor(g, off);
        if (lane == 0)
            goldv[b] = g + crf_start[stag[0]] + crf_end[stag[L - 1]];
    }
}

// ---- K3: 64 blocks (one per sample). Entity segsum + 32-step combine from LDS. ----
__global__ __launch_bounds__(256) void k3_final(
    const float* __restrict__ crf_start,
    const float* __restrict__ crf_end,
    const int* __restrict__ ent_sid,
    const float* __restrict__ ws,
    float* __restrict__ out) {
    const float* featsT = ws;
    const float* ws2    = ws + OFF_WS2;
    const float* goldv  = ws + OFF_G;
    const float* cev    = ws + OFF_CE;
    __shared__ float mats[192 * 8];
    __shared__ float part[256];
    const int b   = blockIdx.x;
    const int tid = threadIdx.x;

    {
        const int4*   s4 = (const int4*)ent_sid;
        const float4* c4 = (const float4*)cev;
        float acc = 0.0f;
#pragma unroll
        for (int i = 0; i < 2; ++i) {
            int4   s = s4[tid * 2 + i];
            float4 c = c4[tid * 2 + i];
            acc += (s.x == b) ? c.x : 0.0f;
            acc += (s.y == b) ? c.y : 0.0f;
            acc += (s.z == b) ? c.z : 0.0f;
            acc += (s.w == b) ? c.w : 0.0f;
        }
        part[tid] = acc;
    }
    if (tid < 192) {
        const float4* src = (const float4*)(ws2 + ((size_t)tid * 64 + b) * 8);
        float4 a = src[0], d = src[1];
        ((float4*)&mats[tid * 8])[0] = a;
        ((float4*)&mats[tid * 8])[1] = d;
    }
    __syncthreads();
    if (tid < 128) part[tid] += part[tid + 128];
    __syncthreads();
    if (tid < 64) {
        float v = part[tid] + part[tid + 64];
#pragma unroll
        for (int off = 32; off >= 1; off >>= 1) v += __shfl_xor(v, off);
        if (tid == 0) part[0] = v;
    }
    __syncthreads();

    if (tid < 64) {
        float a0[NVT];
#pragma unroll
        for (int j = 0; j < NVT; ++j) a0[j] = crf_start[j] + featsT[b * 6 + j];
        float m0 = fmaxf(fmaxf(fmaxf(a0[0], a0[1]), a0[2]),
                         fmaxf(fmaxf(a0[3], a0[4]), a0[5]));
        float q[6];
#pragma unroll
        for (int j = 0; j < NVT; ++j)
            q[j] = __builtin_amdgcn_exp2f((a0[j] - m0) * LOG2E);
        float mAcc = m0 * LOG2E;

#pragma unroll 1
        for (int c = 0; c < 32; ++c) {
            const float* m = &mats[c * 48];
            float4 c0a = ((const float4*)m)[0],  c0b = ((const float4*)m)[1];
            float4 c1a = ((const float4*)m)[2],  c1b = ((const float4*)m)[3];
            float4 c2a = ((const float4*)m)[4],  c2b = ((const float4*)m)[5];
            float4 c3a = ((const float4*)m)[6],  c3b = ((const float4*)m)[7];
            float4 c4a = ((const float4*)m)[8],  c4b = ((const float4*)m)[9];
            float4 c5a = ((const float4*)m)[10], c5b = ((const float4*)m)[11];
            float s0 = c0b.z, s1 = c1b.z, s2 = c2b.z, s3 = c3b.z, s4 = c4b.z, s5 = c5b.z;
            float im = fmaxf(fmaxf(fmaxf(s0, s1), fmaxf(s2, s3)), fmaxf(s4, s5));
            float w0 = q[0] * __builtin_amdgcn_exp2f(s0 - im);
            float w1 = q[1] * __builtin_amdgcn_exp2f(s1 - im);
            float w2 = q[2] * __builtin_amdgcn_exp2f(s2 - im);
            float w3 = q[3] * __builtin_amdgcn_exp2f(s3 - im);
            float w4 = q[4] * __builtin_amdgcn_exp2f(s4 - im);
            float w5 = q[5] * __builtin_amdgcn_exp2f(s5 - im);
            float n0 = c0a.x * w0, n1 = c0a.y * w0, n2 = c0a.z * w0,
                  n3 = c0a.w * w0, n4 = c0b.x * w0, n5 = c0b.y * w0;
            n0 = __builtin_fmaf(c1a.x, w1, n0); n1 = __builtin_fmaf(c1a.y, w1, n1);
            n2 = __builtin_fmaf(c1a.z, w1, n2); n3 = __builtin_fmaf(c1a.w, w1, n3);
            n4 = __builtin_fmaf(c1b.x, w1, n4); n5 = __builtin_fmaf(c1b.y, w1, n5);
            n0 = __builtin_fmaf(c2a.x, w2, n0); n1 = __builtin_fmaf(c2a.y, w2, n1);
            n2 = __builtin_fmaf(c2a.z, w2, n2); n3 = __builtin_fmaf(c2a.w, w2, n3);
            n4 = __builtin_fmaf(c2b.x, w2, n4); n5 = __builtin_fmaf(c2b.y, w2, n5);
            n0 = __builtin_fmaf(c3a.x, w3, n0); n1 = __builtin_fmaf(c3a.y, w3, n1);
            n2 = __builtin_fmaf(c3a.z, w3, n2); n3 = __builtin_fmaf(c3a.w, w3, n3);
            n4 = __builtin_fmaf(c3b.x, w3, n4); n5 = __builtin_fmaf(c3b.y, w3, n5);
            n0 = __builtin_fmaf(c4a.x, w4, n0); n1 = __builtin_fmaf(c4a.y, w4, n1);
            n2 = __builtin_fmaf(c4a.z, w4, n2); n3 = __builtin_fmaf(c4a.w, w4, n3);
            n4 = __builtin_fmaf(c4b.x, w4, n4); n5 = __builtin_fmaf(c4b.y, w4, n5);
            n0 = __builtin_fmaf(c5a.x, w5, n0); n1 = __builtin_fmaf(c5a.y, w5, n1);
            n2 = __builtin_fmaf(c5a.z, w5, n2); n3 = __builtin_fmaf(c5a.w, w5, n3);
            n4 = __builtin_fmaf(c5b.x, w5, n4); n5 = __builtin_fmaf(c5b.y, w5, n5);
            float qm = fmaxf(fmaxf(fmaxf(n0, n1), n2), fmaxf(fmaxf(n3, n4), n5));
            uint32_t eb = __float_as_uint(qm) >> 23;
            float ri = __uint_as_float((uint32_t)(253 - eb) << 23);
            q[0] = n0 * ri; q[1] = n1 * ri; q[2] = n2 * ri;
            q[3] = n3 * ri; q[4] = n4 * ri; q[5] = n5 * ri;
            mAcc += im + (float)((int)eb - 126);
        }

        float zs = 0.0f;
#pragma unroll
        for (int j = 0; j < NVT; ++j)
            zs += q[j] * __builtin_amdgcn_exp2f(crf_end[j] * LOG2E);
        float logZ = LN2 * (mAcc + __builtin_amdgcn_logf(zs));
        if (tid == 0)
            out[b] = logZ - goldv[b] + part[0];
    }
}

extern "C" void kernel_launch(void* const* d_in, const int* in_sizes, int n_in,
                              void* d_out, int out_size, void* d_ws, size_t ws_size,
                              hipStream_t stream) {
    const float* H         = (const float*)d_in[0];
    const float* W_tag     = (const float*)d_in[1];
    const float* b_tag     = (const float*)d_in[2];
    const float* W_type    = (const float*)d_in[3];
    const float* b_type    = (const float*)d_in[4];
    const float* crf_start = (const float*)d_in[5];
    const float* crf_end   = (const float*)d_in[6];
    const float* crf_trans = (const float*)d_in[7];
    const int* tag_ids     = (const int*)d_in[8];
    const int* seq_lens    = (const int*)d_in[9];
    const int* ent_sid     = (const int*)d_in[10];
    const int* ent_st      = (const int*)d_in[11];
    const int* ent_en      = (const int*)d_in[12];
    const int* ent_ty      = (const int*)d_in[13];
    float* out = (float*)d_out;
    float* ws  = (float*)d_ws;

    hipLaunchKernelGGL(k1_tagfeats, dim3(1024), dim3(256), 0, stream,
                       H, W_tag, b_tag, W_type, ws);
    hipLaunchKernelGGL(k2_fused, dim3(NE + 192 + NB), dim3(64), 0, stream,
                       H, b_type, crf_start, crf_end, crf_trans,
                       tag_ids, seq_lens, ent_sid, ent_st, ent_en, ent_ty, ws);
    hipLaunchKernelGGL(k3_final, dim3(NB), dim3(256), 0, stream,
                       crf_start, crf_end, ent_sid, ws, out);
}